// Round 1
// baseline (315.629 us; speedup 1.0000x reference)
//
#include <hip/hip_runtime.h>
#include <hip/hip_bf16.h>
#include <math.h>

#define PI_D 3.14159265358979323846

// Workspace layout (float2 units):
//   tabs[0..1023]    = F     (32x32)  exp(-2pi i rc/32)
//   tabs[1024..2047] = Finv  (32x32)  conj(F)
//   tabs[2048..3071] = tw    (32x32)  exp(-2pi i rc/1024)/1024
//   tabs[3072..4095] = twinv (32x32)  exp(+2pi i rc/1024)
//   kfT at byte offset 65536: H x 32 x 32 complex = filter spectrum, transposed layout

__global__ __launch_bounds__(1024) void fft_tables(float2* tabs) {
    int i = threadIdx.x;            // 0..1023
    int r = i >> 5, c = i & 31;
    double p32 = -2.0 * PI_D * (double)((r * c) & 31) / 32.0;
    float c32 = (float)cos(p32), s32 = (float)sin(p32);
    tabs[i]        = make_float2(c32,  s32);          // F
    tabs[1024 + i] = make_float2(c32, -s32);          // Finv
    double p1024 = -2.0 * PI_D * (double)(r * c) / 1024.0;
    float cN = (float)cos(p1024), sN = (float)sin(p1024);
    tabs[2048 + i] = make_float2(cN / 1024.0f, sN / 1024.0f);  // tw (includes 1/N)
    tabs[3072 + i] = make_float2(cN, -sN);                     // twinv = exp(+2pi i rc/N)
}

// Filter spectrum: kfT[h][k1][k2] = FFT_1024(k[h])[32*k2 + k1]
// = forward four-step: X1 = F * x ; X1 *= exp(-2pi i k1 n2/1024) (=conj(twinv));
//   X2 = X1 * F ; kfT = X2.
__global__ __launch_bounds__(256) void kf_kernel(const float* __restrict__ kin,
                                                 const float2* __restrict__ tabs,
                                                 float2* __restrict__ kfT) {
    __shared__ float  sx[1024];
    __shared__ float2 sA[1024];
    const int h = blockIdx.x, t = threadIdx.x;
    for (int i = t; i < 1024; i += 256) sx[i] = kin[h * 1024 + i];
    __syncthreads();
    const int r = t >> 3, c0 = (t & 7) << 2;

    float2 acc[4];
    for (int j = 0; j < 4; j++) acc[j] = make_float2(0.f, 0.f);
    #pragma unroll 8
    for (int n1 = 0; n1 < 32; n1++) {
        float2 f = tabs[r * 32 + n1];              // F[r][n1]
        for (int j = 0; j < 4; j++) {
            float xv = sx[n1 * 32 + c0 + j];
            acc[j].x += f.x * xv;
            acc[j].y += f.y * xv;
        }
    }
    for (int j = 0; j < 4; j++) {
        float2 w = tabs[3072 + r * 32 + c0 + j];   // twinv; need conj(twinv)
        sA[r * 32 + c0 + j] = make_float2(acc[j].x * w.x + acc[j].y * w.y,
                                          acc[j].y * w.x - acc[j].x * w.y);
    }
    __syncthreads();
    for (int j = 0; j < 4; j++) acc[j] = make_float2(0.f, 0.f);
    #pragma unroll 8
    for (int n2 = 0; n2 < 32; n2++) {
        float2 a = sA[r * 32 + n2];
        for (int j = 0; j < 4; j++) {
            float2 f = tabs[n2 * 32 + c0 + j];     // F[n2][c0+j]
            acc[j].x += a.x * f.x - a.y * f.y;
            acc[j].y += a.x * f.y + a.y * f.x;
        }
    }
    for (int j = 0; j < 4; j++) kfT[h * 1024 + r * 32 + c0 + j] = acc[j];
}

// Main kernel: one (b,h) row of 1024 per block; 256 threads; thread owns
// rows r = t>>3 (one row) x 4 consecutive cols c0..c0+3.
// LDS strides padded (34 for float2, 36 for float) to avoid 8-way bank
// conflicts on the r-indexed broadcast reads while keeping 16B alignment.
__global__ __launch_bounds__(256) void conv_kernel(const float* __restrict__ u,
                                                   const float2* __restrict__ tabs,
                                                   const float2* __restrict__ kfT,
                                                   float* __restrict__ out) {
    __shared__ float  sx[32 * 36];
    __shared__ float2 sF[32 * 34];
    __shared__ float2 sFi[32 * 34];
    __shared__ float2 sA[32 * 34];
    __shared__ float2 sB[32 * 34];

    const int h = blockIdx.x, b = blockIdx.y;
    const int t = threadIdx.x;
    const int r = t >> 3, c0 = (t & 7) << 2;
    const float* up = u + ((size_t)(b * 128 + h)) * 1024;

    for (int i = t; i < 1024; i += 256) {
        int rr = i >> 5, cc = i & 31;
        sx[rr * 36 + cc] = up[i];
        sF[rr * 34 + cc] = tabs[i];
        sFi[rr * 34 + cc] = tabs[1024 + i];
    }
    __syncthreads();

    // ---- Stage A: sA[r][c] = (sum_n1 F[r][n1] * x[n1][c]) * tw[r][c]
    float2 a0, a1, a2, a3;
    a0 = a1 = a2 = a3 = make_float2(0.f, 0.f);
    #pragma unroll 8
    for (int n1 = 0; n1 < 32; n1++) {
        float2 f = sF[r * 34 + n1];
        float4 xv = *(const float4*)&sx[n1 * 36 + c0];
        a0.x += f.x * xv.x; a0.y += f.y * xv.x;
        a1.x += f.x * xv.y; a1.y += f.y * xv.y;
        a2.x += f.x * xv.z; a2.y += f.y * xv.z;
        a3.x += f.x * xv.w; a3.y += f.y * xv.w;
    }
    {
        float4 w01 = *(const float4*)&tabs[2048 + r * 32 + c0];
        float4 w23 = *(const float4*)&tabs[2048 + r * 32 + c0 + 2];
        float2 r0 = make_float2(a0.x * w01.x - a0.y * w01.y, a0.x * w01.y + a0.y * w01.x);
        float2 r1 = make_float2(a1.x * w01.z - a1.y * w01.w, a1.x * w01.w + a1.y * w01.z);
        float2 r2 = make_float2(a2.x * w23.x - a2.y * w23.y, a2.x * w23.y + a2.y * w23.x);
        float2 r3 = make_float2(a3.x * w23.z - a3.y * w23.w, a3.x * w23.w + a3.y * w23.z);
        sA[r * 34 + c0]     = r0;
        sA[r * 34 + c0 + 1] = r1;
        sA[r * 34 + c0 + 2] = r2;
        sA[r * 34 + c0 + 3] = r3;
    }
    __syncthreads();

    // ---- Stage B: sB[r][c] = (sum_n2 sA[r][n2] * F[n2][c]) * kfT[h][r][c]
    a0 = a1 = a2 = a3 = make_float2(0.f, 0.f);
    #pragma unroll 8
    for (int n2 = 0; n2 < 32; n2++) {
        float2 a = sA[r * 34 + n2];
        float4 f01 = *(const float4*)&sF[n2 * 34 + c0];
        float4 f23 = *(const float4*)&sF[n2 * 34 + c0 + 2];
        a0.x += a.x * f01.x - a.y * f01.y; a0.y += a.x * f01.y + a.y * f01.x;
        a1.x += a.x * f01.z - a.y * f01.w; a1.y += a.x * f01.w + a.y * f01.z;
        a2.x += a.x * f23.x - a.y * f23.y; a2.y += a.x * f23.y + a.y * f23.x;
        a3.x += a.x * f23.z - a.y * f23.w; a3.y += a.x * f23.w + a.y * f23.z;
    }
    {
        const float2* kh = kfT + h * 1024 + r * 32 + c0;
        float4 k01 = *(const float4*)&kh[0];
        float4 k23 = *(const float4*)&kh[2];
        float2 r0 = make_float2(a0.x * k01.x - a0.y * k01.y, a0.x * k01.y + a0.y * k01.x);
        float2 r1 = make_float2(a1.x * k01.z - a1.y * k01.w, a1.x * k01.w + a1.y * k01.z);
        float2 r2 = make_float2(a2.x * k23.x - a2.y * k23.y, a2.x * k23.y + a2.y * k23.x);
        float2 r3 = make_float2(a3.x * k23.z - a3.y * k23.w, a3.x * k23.w + a3.y * k23.z);
        sB[r * 34 + c0]     = r0;
        sB[r * 34 + c0 + 1] = r1;
        sB[r * 34 + c0 + 2] = r2;
        sB[r * 34 + c0 + 3] = r3;
    }
    __syncthreads();

    // ---- Stage C: sA[r][c] = (sum_k2 sB[r][k2] * Finv[k2][c]) * twinv[r][c]
    a0 = a1 = a2 = a3 = make_float2(0.f, 0.f);
    #pragma unroll 8
    for (int k2 = 0; k2 < 32; k2++) {
        float2 a = sB[r * 34 + k2];
        float4 f01 = *(const float4*)&sFi[k2 * 34 + c0];
        float4 f23 = *(const float4*)&sFi[k2 * 34 + c0 + 2];
        a0.x += a.x * f01.x - a.y * f01.y; a0.y += a.x * f01.y + a.y * f01.x;
        a1.x += a.x * f01.z - a.y * f01.w; a1.y += a.x * f01.w + a.y * f01.z;
        a2.x += a.x * f23.x - a.y * f23.y; a2.y += a.x * f23.y + a.y * f23.x;
        a3.x += a.x * f23.z - a.y * f23.w; a3.y += a.x * f23.w + a.y * f23.z;
    }
    {
        float4 w01 = *(const float4*)&tabs[3072 + r * 32 + c0];
        float4 w23 = *(const float4*)&tabs[3072 + r * 32 + c0 + 2];
        float2 r0 = make_float2(a0.x * w01.x - a0.y * w01.y, a0.x * w01.y + a0.y * w01.x);
        float2 r1 = make_float2(a1.x * w01.z - a1.y * w01.w, a1.x * w01.w + a1.y * w01.z);
        float2 r2 = make_float2(a2.x * w23.x - a2.y * w23.y, a2.x * w23.y + a2.y * w23.x);
        float2 r3 = make_float2(a3.x * w23.z - a3.y * w23.w, a3.x * w23.w + a3.y * w23.z);
        sA[r * 34 + c0]     = r0;
        sA[r * 34 + c0 + 1] = r1;
        sA[r * 34 + c0 + 2] = r2;
        sA[r * 34 + c0 + 3] = r3;
    }
    __syncthreads();

    // ---- Stage D: y[r][c] = Re( sum_k1 Finv[r][k1] * sA[k1][c] )
    float4 o = make_float4(0.f, 0.f, 0.f, 0.f);
    #pragma unroll 8
    for (int k1 = 0; k1 < 32; k1++) {
        float2 f = sFi[r * 34 + k1];
        float4 a01 = *(const float4*)&sA[k1 * 34 + c0];
        float4 a23 = *(const float4*)&sA[k1 * 34 + c0 + 2];
        o.x += f.x * a01.x - f.y * a01.y;
        o.y += f.x * a01.z - f.y * a01.w;
        o.z += f.x * a23.x - f.y * a23.y;
        o.w += f.x * a23.z - f.y * a23.w;
    }
    *(float4*)&out[((size_t)(b * 128 + h)) * 1024 + r * 32 + c0] = o;
}

extern "C" void kernel_launch(void* const* d_in, const int* in_sizes, int n_in,
                              void* d_out, int out_size, void* d_ws, size_t ws_size,
                              hipStream_t stream) {
    const float* u = (const float*)d_in[0];   // (B=128, H=128, N=1024)
    const float* k = (const float*)d_in[1];   // (H=128, N=1024)
    float* out = (float*)d_out;               // (B, H, N) float32

    float2* tabs = (float2*)d_ws;                         // 32 KB
    float2* kfT  = (float2*)((char*)d_ws + 65536);        // 1 MB

    fft_tables<<<1, 1024, 0, stream>>>(tabs);
    kf_kernel<<<128, 256, 0, stream>>>(k, tabs, kfT);
    conv_kernel<<<dim3(128, 128), 256, 0, stream>>>(u, tabs, kfT, out);
}

// Round 2
// 73.524 us; speedup vs baseline: 4.2929x; 4.2929x over previous
//
#include <hip/hip_runtime.h>
#include <hip/hip_bf16.h>
#include <math.h>

#define PI_D 3.14159265358979323846

typedef __attribute__((ext_vector_type(8))) short short8;
typedef __attribute__((ext_vector_type(16))) float f32x16;

union U {
    unsigned u[4];
    short8 s;
};

struct FragPair {      // one component (re or im) as MFMA operand, split hi/lo, 2 k-tiles
    U h[2];
    U l[2];
};

static __device__ __forceinline__ unsigned short f2bf(float x) {
    union { float f; unsigned u; } v; v.f = x;
    unsigned r = v.u + 0x7FFFu + ((v.u >> 16) & 1u);   // round-to-nearest-even
    return (unsigned short)(r >> 16);
}
static __device__ __forceinline__ float bf2f(unsigned short h) {
    union { unsigned u; float f; } v; v.u = ((unsigned)h) << 16;
    return v.f;
}

#define MFMA(A, B, C) __builtin_amdgcn_mfma_f32_32x32x16_bf16((A).s, (B).s, (C), 0, 0, 0)

// ---------------------------------------------------------------------------
// Workspace layout (bytes):
//   0      : tabs  float2[4096]  (F, Finv, tw, twinv -- legacy layout for kf_kernel)
//   32768  : T1    float2[1024]  (tw permuted to C/D fragment order)
//   49152  : Ftab  uint4 [768]   (bf16 hi/lo fragment tables for F components)
//   65536  : kf_cd float2[128*1024] (filter spectrum, permuted to C/D order)
// ---------------------------------------------------------------------------

__global__ __launch_bounds__(1024) void fft_tables(float2* tabs, float2* T1, uint4* Ftab) {
    int i = threadIdx.x;            // 0..1023
    {
        int r = i >> 5, c = i & 31;
        double p32 = -2.0 * PI_D * (double)((r * c) & 31) / 32.0;
        float c32 = (float)cos(p32), s32 = (float)sin(p32);
        tabs[i]        = make_float2(c32,  s32);          // F
        tabs[1024 + i] = make_float2(c32, -s32);          // Finv
        double p1024 = -2.0 * PI_D * (double)(r * c) / 1024.0;
        float cN = (float)cos(p1024), sN = (float)sin(p1024);
        tabs[2048 + i] = make_float2(cN / 1024.0f, sN / 1024.0f);  // tw
        tabs[3072 + i] = make_float2(cN, -sN);                     // twinv
    }
    {
        // T1[m][l] = tw[l&31][row(m,l)], tw symmetric -> tw(prod)
        int m = i >> 6, l = i & 63;
        int row = (m & 3) + 8 * (m >> 2) + 4 * (l >> 5);
        int prod = (l & 31) * row;
        double ang = -2.0 * PI_D * (double)prod / 1024.0;
        T1[i] = make_float2((float)cos(ang) / 1024.0f, (float)sin(ang) / 1024.0f);
    }
    // Ftab: 6 comps x 2 ktiles x 64 lanes x 4 vgprs, packed bf16 pairs.
    // comp 0/1: hi/lo of re(F)=cos ; 2/3: hi/lo of im(F)=-sin ; 4/5: hi/lo of +sin
    for (int idx = i; idx < 3072; idx += 1024) {
        int c = idx >> 9;
        int rem = idx & 511;
        int t = rem >> 8;
        int sub = rem & 255;
        int l = sub >> 2;
        int v = sub & 3;
        int k0 = 16 * t + 8 * (l >> 5) + 2 * v;
        int j = l & 31;
        unsigned short sh[2];
        for (int q = 0; q < 2; q++) {
            int k = k0 + q;
            double ang = 2.0 * PI_D * (double)((k * j) & 31) / 32.0;
            float re = (float)cos(ang);
            float im = -(float)sin(ang);
            float base = (c < 2) ? re : ((c < 4) ? im : -im);
            unsigned short hh = f2bf(base);
            if (c & 1) {
                sh[q] = f2bf(base - bf2f(hh));   // lo part
            } else {
                sh[q] = hh;                       // hi part
            }
        }
        unsigned packed = (unsigned)sh[0] | ((unsigned)sh[1] << 16);
        ((unsigned*)Ftab)[((c * 2 + t) * 64 + l) * 4 + v] = packed;
    }
}

// Filter spectrum kfT[h][k1][k2] = FFT_1024(k[h])[32*k2+k1], written permuted:
// kf_cd[h][m][l] = kfT[h][l&31][row(m,l)]
__global__ __launch_bounds__(256) void kf_kernel(const float* __restrict__ kin,
                                                 const float2* __restrict__ tabs,
                                                 float2* __restrict__ kf_cd) {
    __shared__ float  sx[1024];
    __shared__ float2 sA[1024];
    const int h = blockIdx.x, t = threadIdx.x;
    for (int i = t; i < 1024; i += 256) sx[i] = kin[h * 1024 + i];
    __syncthreads();
    const int r = t >> 3, c0 = (t & 7) << 2;

    float2 acc[4];
    for (int j = 0; j < 4; j++) acc[j] = make_float2(0.f, 0.f);
    #pragma unroll 8
    for (int n1 = 0; n1 < 32; n1++) {
        float2 f = tabs[r * 32 + n1];
        for (int j = 0; j < 4; j++) {
            float xv = sx[n1 * 32 + c0 + j];
            acc[j].x += f.x * xv;
            acc[j].y += f.y * xv;
        }
    }
    for (int j = 0; j < 4; j++) {
        float2 w = tabs[3072 + r * 32 + c0 + j];   // conj(twinv) = exp(-2pi i rc/N)
        sA[r * 32 + c0 + j] = make_float2(acc[j].x * w.x + acc[j].y * w.y,
                                          acc[j].y * w.x - acc[j].x * w.y);
    }
    __syncthreads();
    for (int j = 0; j < 4; j++) acc[j] = make_float2(0.f, 0.f);
    #pragma unroll 8
    for (int n2 = 0; n2 < 32; n2++) {
        float2 a = sA[r * 32 + n2];
        for (int j = 0; j < 4; j++) {
            float2 f = tabs[n2 * 32 + c0 + j];
            acc[j].x += a.x * f.x - a.y * f.y;
            acc[j].y += a.x * f.y + a.y * f.x;
        }
    }
    for (int j = 0; j < 4; j++) {
        int k2 = c0 + j;                          // col index
        int m = (k2 & 3) | ((k2 >> 3) << 2);
        int hl = (k2 >> 2) & 1;
        kf_cd[h * 1024 + m * 64 + hl * 32 + r] = acc[j];
    }
}

// Convert C/D accumulator (col=lane&31, row=(m&3)+8*(m>>2)+4*(lane>>5)) into
// an A/B fragment (k = 8*(lane>>5)+e within each 16-wide k-tile), hi/lo bf16.
static __device__ __forceinline__ void convert(const f32x16& acc, bool lolane, FragPair& out) {
    float bvals[16];
    #pragma unroll
    for (int m = 0; m < 4; m++) {
        float x = acc[m],      y = acc[4 + m];
        float xs = __shfl_xor(x, 32), ys = __shfl_xor(y, 32);
        bvals[m]     = lolane ? x  : ys;   // rows m / 8+m
        bvals[4 + m] = lolane ? xs : y;    // rows 4+m / 12+m
        float p = acc[8 + m],  q = acc[12 + m];
        float ps = __shfl_xor(p, 32), qs = __shfl_xor(q, 32);
        bvals[8 + m]  = lolane ? p  : qs;  // rows 16+m / 24+m
        bvals[12 + m] = lolane ? ps : q;   // rows 20+m / 28+m
    }
    #pragma unroll
    for (int kt = 0; kt < 2; kt++) {
        #pragma unroll
        for (int v = 0; v < 4; v++) {
            float e0 = bvals[kt * 8 + 2 * v], e1 = bvals[kt * 8 + 2 * v + 1];
            unsigned short h0 = f2bf(e0), h1 = f2bf(e1);
            unsigned short l0 = f2bf(e0 - bf2f(h0)), l1 = f2bf(e1 - bf2f(h1));
            out.h[kt].u[v] = (unsigned)h0 | ((unsigned)h1 << 16);
            out.l[kt].u[v] = (unsigned)l0 | ((unsigned)l1 << 16);
        }
    }
}

__global__ __launch_bounds__(256, 2) void conv_mfma(const float* __restrict__ u,
                                                    const float2* __restrict__ T1,
                                                    const uint4* __restrict__ Ftab,
                                                    const float2* __restrict__ KF,
                                                    float* __restrict__ out) {
    const int lane = threadIdx.x & 63;
    const int wave = threadIdx.x >> 6;
    const int w = blockIdx.x * 4 + wave;     // 0..4095, 4 tiles each
    const int h = w >> 5;                    // all 4 tiles share h
    const int col = lane & 31;
    const int hl = lane >> 5;
    const bool lolane = (hl == 0);

    // Fixed F fragment tables (bf16 hi/lo), resident in registers.
    U F[6][2];
    #pragma unroll
    for (int c = 0; c < 6; c++)
        #pragma unroll
        for (int t = 0; t < 2; t++) {
            uint4 raw = Ftab[(c * 2 + t) * 64 + lane];
            F[c][t].u[0] = raw.x; F[c][t].u[1] = raw.y;
            F[c][t].u[2] = raw.z; F[c][t].u[3] = raw.w;
        }
    // Twiddle (C/D order) and filter spectrum for this h, resident.
    float2 t1[16], kf[16];
    #pragma unroll
    for (int m = 0; m < 16; m++) {
        t1[m] = T1[m * 64 + lane];
        kf[m] = KF[h * 1024 + m * 64 + lane];
    }

    const f32x16 Z16 = {0,0,0,0,0,0,0,0,0,0,0,0,0,0,0,0};

    for (int i = 0; i < 4; i++) {
        const int tile = w * 4 + i;
        const int b = tile & 127;
        const float* up = u + ((size_t)(b * 128 + h) << 10);

        // ---- Stage 1 input: A = X^T, direct from global, hi/lo bf16.
        U Ah[2], Al[2];
        #pragma unroll
        for (int t = 0; t < 2; t++) {
            float xv[8];
            #pragma unroll
            for (int e = 0; e < 8; e++)
                xv[e] = up[(16 * t + 8 * hl + e) * 32 + col];
            #pragma unroll
            for (int v = 0; v < 4; v++) {
                unsigned short h0 = f2bf(xv[2 * v]), h1 = f2bf(xv[2 * v + 1]);
                unsigned short l0 = f2bf(xv[2 * v] - bf2f(h0));
                unsigned short l1 = f2bf(xv[2 * v + 1] - bf2f(h1));
                Ah[t].u[v] = (unsigned)h0 | ((unsigned)h1 << 16);
                Al[t].u[v] = (unsigned)l0 | ((unsigned)l1 << 16);
            }
        }

        // ---- Stage 1: Y^T = X^T @ F   (Yr = X@Fre, Yi = X@Fim)
        f32x16 aR = Z16, aI = Z16;
        #pragma unroll
        for (int t = 0; t < 2; t++) {
            aR = MFMA(Ah[t], F[0][t], aR); aR = MFMA(Ah[t], F[1][t], aR); aR = MFMA(Al[t], F[0][t], aR);
            aI = MFMA(Ah[t], F[2][t], aI); aI = MFMA(Ah[t], F[3][t], aI); aI = MFMA(Al[t], F[2][t], aI);
        }
        // twiddle tw (includes 1/N)
        #pragma unroll
        for (int m = 0; m < 16; m++) {
            float rr = aR[m] * t1[m].x - aI[m] * t1[m].y;
            float ii = aR[m] * t1[m].y + aI[m] * t1[m].x;
            aR[m] = rr; aI[m] = ii;
        }
        FragPair Yr, Yi;
        convert(aR, lolane, Yr);
        convert(aI, lolane, Yi);

        // ---- Stage 3: Z^T = F @ Y^T  (Zr = Fre@Yr + (+sin)@Yi ; Zi = Fre@Yi + Fim@Yr)
        f32x16 bR = Z16, bI = Z16;
        #pragma unroll
        for (int t = 0; t < 2; t++) {
            bR = MFMA(F[0][t], Yr.h[t], bR); bR = MFMA(F[0][t], Yr.l[t], bR); bR = MFMA(F[1][t], Yr.h[t], bR);
            bR = MFMA(F[4][t], Yi.h[t], bR); bR = MFMA(F[4][t], Yi.l[t], bR); bR = MFMA(F[5][t], Yi.h[t], bR);
            bI = MFMA(F[0][t], Yi.h[t], bI); bI = MFMA(F[0][t], Yi.l[t], bI); bI = MFMA(F[1][t], Yi.h[t], bI);
            bI = MFMA(F[2][t], Yr.h[t], bI); bI = MFMA(F[2][t], Yr.l[t], bI); bI = MFMA(F[3][t], Yr.h[t], bI);
        }
        // filter spectrum multiply
        #pragma unroll
        for (int m = 0; m < 16; m++) {
            float rr = bR[m] * kf[m].x - bI[m] * kf[m].y;
            float ii = bR[m] * kf[m].y + bI[m] * kf[m].x;
            bR[m] = rr; bI[m] = ii;
        }
        FragPair Zr, Zi;
        convert(bR, lolane, Zr);
        convert(bI, lolane, Zi);

        // ---- Stage 5: W = Z @ Finv  (Wr = Zr@Fre + Zi@Fim ; Wi = Zr@(+sin) + Zi@Fre)
        aR = Z16; aI = Z16;
        #pragma unroll
        for (int t = 0; t < 2; t++) {
            aR = MFMA(Zr.h[t], F[0][t], aR); aR = MFMA(Zr.h[t], F[1][t], aR); aR = MFMA(Zr.l[t], F[0][t], aR);
            aR = MFMA(Zi.h[t], F[2][t], aR); aR = MFMA(Zi.h[t], F[3][t], aR); aR = MFMA(Zi.l[t], F[2][t], aR);
            aI = MFMA(Zr.h[t], F[4][t], aI); aI = MFMA(Zr.h[t], F[5][t], aI); aI = MFMA(Zr.l[t], F[4][t], aI);
            aI = MFMA(Zi.h[t], F[0][t], aI); aI = MFMA(Zi.h[t], F[1][t], aI); aI = MFMA(Zi.l[t], F[0][t], aI);
        }
        // twinv = 1024 * conj(tw)
        #pragma unroll
        for (int m = 0; m < 16; m++) {
            float rr = 1024.0f * (aR[m] * t1[m].x + aI[m] * t1[m].y);
            float ii = 1024.0f * (aI[m] * t1[m].x - aR[m] * t1[m].y);
            aR[m] = rr; aI[m] = ii;
        }
        FragPair Wr, Wi;
        convert(aR, lolane, Wr);
        convert(aI, lolane, Wi);

        // ---- Stage 7: y = Re(Finv @ W) = Fre@Wr + Fim@Wi
        f32x16 yR = Z16;
        #pragma unroll
        for (int t = 0; t < 2; t++) {
            yR = MFMA(F[0][t], Wr.h[t], yR); yR = MFMA(F[0][t], Wr.l[t], yR); yR = MFMA(F[1][t], Wr.h[t], yR);
            yR = MFMA(F[2][t], Wi.h[t], yR); yR = MFMA(F[2][t], Wi.l[t], yR); yR = MFMA(F[3][t], Wi.h[t], yR);
        }
        float* op = out + ((size_t)(b * 128 + h) << 10);
        #pragma unroll
        for (int m = 0; m < 16; m++)
            op[((m & 3) + 8 * (m >> 2) + 4 * hl) * 32 + col] = yR[m];
    }
}

extern "C" void kernel_launch(void* const* d_in, const int* in_sizes, int n_in,
                              void* d_out, int out_size, void* d_ws, size_t ws_size,
                              hipStream_t stream) {
    const float* u = (const float*)d_in[0];   // (B=128, H=128, N=1024)
    const float* k = (const float*)d_in[1];   // (H=128, N=1024)
    float* out = (float*)d_out;               // (B, H, N) float32

    float2* tabs  = (float2*)d_ws;                          // 32 KB legacy tables
    float2* T1    = (float2*)((char*)d_ws + 32768);         // 8 KB
    uint4*  Ftab  = (uint4*)((char*)d_ws + 49152);          // 12 KB
    float2* kf_cd = (float2*)((char*)d_ws + 65536);         // 1 MB

    fft_tables<<<1, 1024, 0, stream>>>(tabs, T1, Ftab);
    kf_kernel<<<128, 256, 0, stream>>>(k, tabs, kf_cd);
    conv_mfma<<<1024, 256, 0, stream>>>(u, T1, Ftab, kf_cd, out);
}

// Round 3
// 54.227 us; speedup vs baseline: 5.8205x; 1.3559x over previous
//
#include <hip/hip_runtime.h>
#include <hip/hip_bf16.h>
#include <math.h>

typedef __attribute__((ext_vector_type(8))) short short8;
typedef __attribute__((ext_vector_type(16))) float f32x16;

union U {
    unsigned u[4];
    short8 s;
};

struct FragH {         // one component (re or im) bf16 operand, 2 k-tiles
    U f[2];
};

static __device__ __forceinline__ unsigned short f2bf(float x) {
    __bf16 b = (__bf16)x;                       // RNE, native v_cvt on gfx950
    return __builtin_bit_cast(unsigned short, b);
}
static __device__ __forceinline__ float bf2f(unsigned short h) {
    return __builtin_bit_cast(float, (unsigned)h << 16);
}
static __device__ __forceinline__ unsigned packbf(float a, float b) {
    return (unsigned)f2bf(a) | ((unsigned)f2bf(b) << 16);
}

#define MFMA(A, B, C) __builtin_amdgcn_mfma_f32_32x32x16_bf16((A).s, (B).s, (C), 0, 0, 0)

// ---------------------------------------------------------------------------
// Workspace layout (bytes):
//   0      : tabs  float2[4096]  (F, Finv, tw, twinv -- legacy layout for kf_kernel)
//   32768  : T1    float2[1024]  (tw permuted to C/D fragment order)
//   49152  : Ftab  uint4 [768]   (bf16 hi/lo fragment tables for F components)
//   65536  : kf_cd float2[128*1024] (filter spectrum, permuted to C/D order)
// ---------------------------------------------------------------------------

__global__ __launch_bounds__(256) void fft_tables(float2* tabs, float2* T1, uint4* Ftab) {
    int gid = blockIdx.x * 256 + threadIdx.x;       // grid 16*256 = 4096
    if (gid < 1024) {
        int i = gid;
        int r = i >> 5, c = i & 31;
        float s32, c32;
        sincospif((float)((r * c) & 31) / 16.0f, &s32, &c32);
        s32 = -s32;                                  // exp(-2pi i rc/32)
        tabs[i]        = make_float2(c32,  s32);     // F
        tabs[1024 + i] = make_float2(c32, -s32);     // Finv
        float sN, cN;
        sincospif((float)(r * c) / 512.0f, &sN, &cN);
        sN = -sN;                                    // exp(-2pi i rc/1024)
        tabs[2048 + i] = make_float2(cN / 1024.0f, sN / 1024.0f);  // tw
        tabs[3072 + i] = make_float2(cN, -sN);                     // twinv
        // T1[m][l] = tw[l&31][row(m,l)] (tw symmetric)
        int m = i >> 6, l = i & 63;
        int row = (m & 3) + 8 * (m >> 2) + 4 * (l >> 5);
        int prod = (l & 31) * row;
        float st, ct;
        sincospif((float)prod / 512.0f, &st, &ct);
        T1[i] = make_float2(ct / 1024.0f, -st / 1024.0f);
    }
    if (gid < 3072) {
        // Ftab: 6 comps x 2 ktiles x 64 lanes x 4 vgprs, packed bf16 pairs.
        // comp 0/1: hi/lo of re(F)=cos ; 2/3: hi/lo of im(F)=-sin ; 4/5: hi/lo of +sin
        int c = gid >> 9;
        int rem = gid & 511;
        int t = rem >> 8;
        int sub = rem & 255;
        int l = sub >> 2;
        int v = sub & 3;
        int k0 = 16 * t + 8 * (l >> 5) + 2 * v;
        int j = l & 31;
        unsigned short sh[2];
        for (int q = 0; q < 2; q++) {
            int k = k0 + q;
            float sa, ca;
            sincospif((float)((k * j) & 31) / 16.0f, &sa, &ca);
            float re = ca, im = -sa;
            float base = (c < 2) ? re : ((c < 4) ? im : -im);
            unsigned short hh = f2bf(base);
            sh[q] = (c & 1) ? f2bf(base - bf2f(hh)) : hh;
        }
        ((unsigned*)Ftab)[((c * 2 + t) * 64 + l) * 4 + v] =
            (unsigned)sh[0] | ((unsigned)sh[1] << 16);
    }
}

// Filter spectrum kfT[h][k1][k2] = FFT_1024(k[h])[32*k2+k1], written permuted:
// kf_cd[h][m][l] = kfT[h][l&31][row(m,l)]
__global__ __launch_bounds__(256) void kf_kernel(const float* __restrict__ kin,
                                                 const float2* __restrict__ tabs,
                                                 float2* __restrict__ kf_cd) {
    __shared__ float  sx[1024];
    __shared__ float2 sA[1024];
    const int h = blockIdx.x, t = threadIdx.x;
    for (int i = t; i < 1024; i += 256) sx[i] = kin[h * 1024 + i];
    __syncthreads();
    const int r = t >> 3, c0 = (t & 7) << 2;

    float2 acc[4];
    for (int j = 0; j < 4; j++) acc[j] = make_float2(0.f, 0.f);
    #pragma unroll 8
    for (int n1 = 0; n1 < 32; n1++) {
        float2 f = tabs[r * 32 + n1];
        for (int j = 0; j < 4; j++) {
            float xv = sx[n1 * 32 + c0 + j];
            acc[j].x += f.x * xv;
            acc[j].y += f.y * xv;
        }
    }
    for (int j = 0; j < 4; j++) {
        float2 w = tabs[3072 + r * 32 + c0 + j];   // conj -> exp(-2pi i rc/N)
        sA[r * 32 + c0 + j] = make_float2(acc[j].x * w.x + acc[j].y * w.y,
                                          acc[j].y * w.x - acc[j].x * w.y);
    }
    __syncthreads();
    for (int j = 0; j < 4; j++) acc[j] = make_float2(0.f, 0.f);
    #pragma unroll 8
    for (int n2 = 0; n2 < 32; n2++) {
        float2 a = sA[r * 32 + n2];
        for (int j = 0; j < 4; j++) {
            float2 f = tabs[n2 * 32 + c0 + j];
            acc[j].x += a.x * f.x - a.y * f.y;
            acc[j].y += a.x * f.y + a.y * f.x;
        }
    }
    for (int j = 0; j < 4; j++) {
        int k2 = c0 + j;
        int m = (k2 & 3) | ((k2 >> 3) << 2);
        int hl = (k2 >> 2) & 1;
        kf_cd[h * 1024 + m * 64 + hl * 32 + r] = acc[j];
    }
}

// C/D accumulator (col=lane&31, row=(m&3)+8*(m>>2)+4*(lane>>5)) -> bf16 A/B
// fragment (k = 16t+8*(lane>>5)+e). Pack to bf16 pairs FIRST, then one packed
// shfl per cross-half word.
static __device__ __forceinline__ void convertH(const f32x16& acc, bool hihalf, FragH& out) {
    unsigned P[8];
    #pragma unroll
    for (int j = 0; j < 8; j++) P[j] = packbf(acc[2 * j], acc[2 * j + 1]);
    #pragma unroll
    for (int t = 0; t < 2; t++) {
        unsigned a0 = P[4 * t + 0], a1 = P[4 * t + 1];
        unsigned b0 = P[4 * t + 2], b1 = P[4 * t + 3];
        unsigned a0x = __shfl_xor(a0, 32), a1x = __shfl_xor(a1, 32);
        unsigned b0x = __shfl_xor(b0, 32), b1x = __shfl_xor(b1, 32);
        out.f[t].u[0] = hihalf ? b0x : a0;
        out.f[t].u[1] = hihalf ? b1x : a1;
        out.f[t].u[2] = hihalf ? b0  : a0x;
        out.f[t].u[3] = hihalf ? b1  : a1x;
    }
}

__global__ __launch_bounds__(256, 2) void conv_mfma(const float* __restrict__ u,
                                                    const float2* __restrict__ T1,
                                                    const uint4* __restrict__ Ftab,
                                                    const float2* __restrict__ KF,
                                                    float* __restrict__ out) {
    const int lane = threadIdx.x & 63;
    const int wave = threadIdx.x >> 6;
    const int w = blockIdx.x * 4 + wave;     // 0..8191, 2 tiles each
    const int h = w >> 6;                    // both tiles share h
    const int col = lane & 31;
    const int hl = lane >> 5;
    const bool hihalf = (hl != 0);

    // Fixed F fragment tables (bf16 hi/lo), register-resident.
    U F[6][2];
    #pragma unroll
    for (int c = 0; c < 6; c++)
        #pragma unroll
        for (int t = 0; t < 2; t++) {
            uint4 raw = Ftab[(c * 2 + t) * 64 + lane];
            F[c][t].u[0] = raw.x; F[c][t].u[1] = raw.y;
            F[c][t].u[2] = raw.z; F[c][t].u[3] = raw.w;
        }
    float2 t1[16], kf[16];
    #pragma unroll
    for (int m = 0; m < 16; m++) {
        t1[m] = T1[m * 64 + lane];
        kf[m] = KF[h * 1024 + m * 64 + lane];
    }

    const f32x16 Z16 = {0,0,0,0,0,0,0,0,0,0,0,0,0,0,0,0};

    for (int i = 0; i < 2; i++) {
        const int tile = w * 2 + i;
        const int b = tile & 127;
        const float* up = u + ((size_t)(b * 128 + h) << 10);

        // ---- Input: A = X^T direct from global, hi/lo bf16 (exact data, keep split).
        U Ah[2], Al[2];
        #pragma unroll
        for (int t = 0; t < 2; t++) {
            float xv[8];
            #pragma unroll
            for (int e = 0; e < 8; e++)
                xv[e] = up[(16 * t + 8 * hl + e) * 32 + col];
            #pragma unroll
            for (int v = 0; v < 4; v++) {
                unsigned short h0 = f2bf(xv[2 * v]), h1 = f2bf(xv[2 * v + 1]);
                Ah[t].u[v] = (unsigned)h0 | ((unsigned)h1 << 16);
                Al[t].u[v] = packbf(xv[2 * v] - bf2f(h0), xv[2 * v + 1] - bf2f(h1));
            }
        }

        // ---- Stage 1: Y^T = X^T @ F
        f32x16 aR = Z16, aI = Z16;
        #pragma unroll
        for (int t = 0; t < 2; t++) {
            aR = MFMA(Ah[t], F[0][t], aR); aR = MFMA(Al[t], F[0][t], aR); aR = MFMA(Ah[t], F[1][t], aR);
            aI = MFMA(Ah[t], F[2][t], aI); aI = MFMA(Al[t], F[2][t], aI); aI = MFMA(Ah[t], F[3][t], aI);
        }
        #pragma unroll
        for (int m = 0; m < 16; m++) {                 // twiddle tw (has 1/N)
            float rr = aR[m] * t1[m].x - aI[m] * t1[m].y;
            float ii = aR[m] * t1[m].y + aI[m] * t1[m].x;
            aR[m] = rr; aI[m] = ii;
        }
        FragH Yr, Yi;
        convertH(aR, hihalf, Yr);
        convertH(aI, hihalf, Yi);

        // ---- Stage 3: Z^T = F @ Y^T  (Zr = Fre@Yr - Fim@Yi ; Zi = Fre@Yi + Fim@Yr)
        f32x16 bR = Z16, bI = Z16;
        #pragma unroll
        for (int t = 0; t < 2; t++) {
            bR = MFMA(F[0][t], Yr.f[t], bR); bR = MFMA(F[1][t], Yr.f[t], bR);
            bR = MFMA(F[4][t], Yi.f[t], bR); bR = MFMA(F[5][t], Yi.f[t], bR);
            bI = MFMA(F[0][t], Yi.f[t], bI); bI = MFMA(F[1][t], Yi.f[t], bI);
            bI = MFMA(F[2][t], Yr.f[t], bI); bI = MFMA(F[3][t], Yr.f[t], bI);
        }
        #pragma unroll
        for (int m = 0; m < 16; m++) {                 // filter spectrum
            float rr = bR[m] * kf[m].x - bI[m] * kf[m].y;
            float ii = bR[m] * kf[m].y + bI[m] * kf[m].x;
            bR[m] = rr; bI[m] = ii;
        }
        FragH Zr, Zi;
        convertH(bR, hihalf, Zr);
        convertH(bI, hihalf, Zi);

        // ---- Stage 5: W = Z @ Finv
        aR = Z16; aI = Z16;
        #pragma unroll
        for (int t = 0; t < 2; t++) {
            aR = MFMA(Zr.f[t], F[0][t], aR); aR = MFMA(Zr.f[t], F[1][t], aR);
            aR = MFMA(Zi.f[t], F[2][t], aR); aR = MFMA(Zi.f[t], F[3][t], aR);
            aI = MFMA(Zr.f[t], F[4][t], aI); aI = MFMA(Zr.f[t], F[5][t], aI);
            aI = MFMA(Zi.f[t], F[0][t], aI); aI = MFMA(Zi.f[t], F[1][t], aI);
        }
        #pragma unroll
        for (int m = 0; m < 16; m++) {                 // twinv = 1024*conj(tw)
            float rr = 1024.0f * (aR[m] * t1[m].x + aI[m] * t1[m].y);
            float ii = 1024.0f * (aI[m] * t1[m].x - aR[m] * t1[m].y);
            aR[m] = rr; aI[m] = ii;
        }
        FragH Wr, Wi;
        convertH(aR, hihalf, Wr);
        convertH(aI, hihalf, Wi);

        // ---- Stage 7: y = Re(Finv @ W) = Fre@Wr + Fim@Wi
        f32x16 yR = Z16;
        #pragma unroll
        for (int t = 0; t < 2; t++) {
            yR = MFMA(F[0][t], Wr.f[t], yR); yR = MFMA(F[1][t], Wr.f[t], yR);
            yR = MFMA(F[2][t], Wi.f[t], yR); yR = MFMA(F[3][t], Wi.f[t], yR);
        }
        float* op = out + ((size_t)(b * 128 + h) << 10);
        #pragma unroll
        for (int m = 0; m < 16; m++)
            op[((m & 3) + 8 * (m >> 2) + 4 * hl) * 32 + col] = yR[m];
    }
}

extern "C" void kernel_launch(void* const* d_in, const int* in_sizes, int n_in,
                              void* d_out, int out_size, void* d_ws, size_t ws_size,
                              hipStream_t stream) {
    const float* u = (const float*)d_in[0];   // (B=128, H=128, N=1024)
    const float* k = (const float*)d_in[1];   // (H=128, N=1024)
    float* out = (float*)d_out;               // (B, H, N) float32

    float2* tabs  = (float2*)d_ws;
    float2* T1    = (float2*)((char*)d_ws + 32768);
    uint4*  Ftab  = (uint4*)((char*)d_ws + 49152);
    float2* kf_cd = (float2*)((char*)d_ws + 65536);

    fft_tables<<<16, 256, 0, stream>>>(tabs, T1, Ftab);
    kf_kernel<<<128, 256, 0, stream>>>(k, tabs, kf_cd);
    conv_mfma<<<2048, 256, 0, stream>>>(u, T1, Ftab, kf_cd, out);
}